// Round 7
// baseline (8437.112 us; speedup 1.0000x reference)
//
#include <hip/hip_runtime.h>
#include <hip/hip_bf16.h>
#include <math.h>

// SpatialTemporalModel: GCN(2-layer) x24 -> LSTM(128) -> MLP head.
// Round 7: k_h2lstm de-bottlenecked: (a) SoA hi/lo storage for v and h
// (vhi/vlo, hhi/hlo) -> staging is plain uint4 copies, no bit-repack VALU;
// (b) LSTM MFMA processes the two 32-row subtiles sequentially (acc 128->64
// regs) + __launch_bounds__(256,3) -> 3 blocks/CU instead of 2.

typedef short s16x8 __attribute__((ext_vector_type(8)));
typedef float f32x16 __attribute__((ext_vector_type(16)));
typedef unsigned long long u64;
typedef unsigned short u16;
union AF { s16x8 v; u64 q[2]; uint4 u4; };

__device__ __forceinline__ float sigf(float x) { return 1.f / (1.f + __expf(-x)); }
__device__ __forceinline__ float tanhfast(float x) { return 1.f - 2.f / (1.f + __expf(2.f * x)); }

// round-to-nearest-even f32 -> bf16 bits
__device__ __forceinline__ unsigned bfr(float x) {
    union { float f; unsigned u; } c; c.f = x;
    return (c.u + 0x7fffu + ((c.u >> 16) & 1u)) >> 16;
}
__device__ __forceinline__ void bsplit(float x, u16& hi, u16& lo) {
    unsigned h = bfr(x);
    union { unsigned u; float f; } hf; hf.u = h << 16;
    hi = (u16)h;
    lo = (u16)bfr(x - hf.f);
}
__device__ __forceinline__ float bf2f(u16 b) {
    union { unsigned u; float f; } c; c.u = ((unsigned)b) << 16;
    return c.f;
}

// ---------------- CSR build ----------------
__global__ void k_count(const int* __restrict__ dst, int E, int* __restrict__ deg) {
    int e = blockIdx.x * blockDim.x + threadIdx.x;
    if (e < E) atomicAdd(&deg[dst[e]], 1);
}

__global__ void k_dinv(const int* __restrict__ deg, float* __restrict__ dinv, int N) {
    int v = blockIdx.x * blockDim.x + threadIdx.x;
    if (v < N) dinv[v] = rsqrtf((float)deg[v] + 1.0f);
}

__global__ __launch_bounds__(256) void k_scan_part(const int* __restrict__ deg, int* __restrict__ partial, int N) {
    int tid = threadIdx.x;
    int i = blockIdx.x * 256 + tid;
    int v = (i < N) ? deg[i] : 0;
    int s = v;
#pragma unroll
    for (int off = 1; off < 64; off <<= 1) s += __shfl_xor(s, off, 64);
    __shared__ int ws[4];
    if ((tid & 63) == 0) ws[tid >> 6] = s;
    __syncthreads();
    if (tid == 0) partial[blockIdx.x] = ws[0] + ws[1] + ws[2] + ws[3];
}

__global__ __launch_bounds__(256) void k_scan_top(int* __restrict__ partial, int nb) {
    __shared__ int sm[256];
    int t = threadIdx.x;
    int x = (t < nb) ? partial[t] : 0;
    sm[t] = x;
    __syncthreads();
#pragma unroll
    for (int off = 1; off < 256; off <<= 1) {
        int y = (t >= off) ? sm[t - off] : 0;
        __syncthreads();
        sm[t] += y;
        __syncthreads();
    }
    if (t < nb) partial[t] = sm[t] - x;  // exclusive
}

__global__ __launch_bounds__(256) void k_scan_fill(const int* __restrict__ deg, const int* __restrict__ partial,
                                                   int* __restrict__ row_ptr, int* __restrict__ cursor, int N) {
    int tid = threadIdx.x;
    int lane = tid & 63;
    int wv = tid >> 6;
    int i = blockIdx.x * 256 + tid;
    int v = (i < N) ? deg[i] : 0;
    int incl = v;
#pragma unroll
    for (int off = 1; off < 64; off <<= 1) {
        int y = __shfl_up(incl, off, 64);
        if (lane >= off) incl += y;
    }
    __shared__ int ws[4];
    if (lane == 63) ws[wv] = incl;
    __syncthreads();
    int woff = 0;
    for (int w = 0; w < wv; ++w) woff += ws[w];
    int excl = incl - v + woff + partial[blockIdx.x];
    if (i < N) {
        row_ptr[i] = excl;
        cursor[i] = excl;
        if (i == N - 1) row_ptr[N] = excl + v;
    }
}

__global__ void k_fill_range(const int* __restrict__ src, const int* __restrict__ dst, int E,
                             int* __restrict__ cursor, int* __restrict__ col, int lo, int hi) {
    int e = blockIdx.x * blockDim.x + threadIdx.x;
    if (e < E) {
        int d = dst[e];
        if (d >= lo && d < hi) {
            int p = atomicAdd(&cursor[d], 1);
            col[p] = src[e];
        }
    }
}

// ---------------- weight prep ----------------
__global__ void k_wprep(const float* __restrict__ W_ih, const float* __restrict__ W_hh,
                        u16* __restrict__ whi, u16* __restrict__ wlo) {
    int i = blockIdx.x * 256 + threadIdx.x;
    if (i >= 512 * 192) return;
    int g = i / 192, k = i - g * 192;
    float wv = (k < 64) ? W_ih[g * 64 + k] : W_hh[g * 128 + (k - 64)];
    u16 h, l;
    bsplit(wv, h, l);
    whi[i] = h;
    wlo[i] = l;
}

__global__ void k_w2prep(const float* __restrict__ W2,
                         u16* __restrict__ w2thi, u16* __restrict__ w2tlo) {
    int i = blockIdx.x * 256 + threadIdx.x;
    if (i >= 64 * 64) return;
    int c = i >> 6, k = i & 63;
    u16 h, l;
    bsplit(W2[k * 64 + c], h, l);
    w2thi[c * 64 + k] = h;
    w2tlo[c * 64 + k] = l;
}

// ---------------- fused layer-1: agg16 + h1 GEMM in-wave ----------------
__global__ __launch_bounds__(256) void k_gcn1(const float* __restrict__ x, const float* __restrict__ dinv,
                                              const int* __restrict__ row_ptr, const int* __restrict__ col,
                                              const float* __restrict__ W1, const float* __restrict__ b1,
                                              u16* __restrict__ h1bf, int N) {
    __shared__ float w[16 * 64];
    __shared__ float uu[4][16];
    int tid = threadIdx.x;
    ((float4*)w)[tid] = ((const float4*)W1)[tid];
    __syncthreads();
    int lane = tid & 63;
    int wv = tid >> 6;
    int v = blockIdx.x * 4 + wv;
    if (v >= N) return;
    int cg = lane & 7;   // channel pair 2cg, 2cg+1
    int eg = lane >> 3;  // 8 edge groups
    int b = row_ptr[v];
    int e = row_ptr[v + 1];
    float s0 = 0.f, s1 = 0.f;
#pragma unroll 2
    for (int i = b + eg; i < e; i += 8) {
        int c = col[i];
        float2 xv = *(const float2*)(x + (size_t)c * 16 + 2 * cg);
        float dc = dinv[c];
        s0 = fmaf(dc, xv.x, s0);
        s1 = fmaf(dc, xv.y, s1);
    }
    s0 += __shfl_xor(s0, 8, 64);  s1 += __shfl_xor(s1, 8, 64);
    s0 += __shfl_xor(s0, 16, 64); s1 += __shfl_xor(s1, 16, 64);
    s0 += __shfl_xor(s0, 32, 64); s1 += __shfl_xor(s1, 32, 64);
    float dv = dinv[v];
    if (eg == 0) {
        float2 xv = *(const float2*)(x + (size_t)v * 16 + 2 * cg);
        uu[wv][2 * cg]     = dv * fmaf(dv, xv.x, s0);
        uu[wv][2 * cg + 1] = dv * fmaf(dv, xv.y, s1);
    }
    float a = b1[lane];
#pragma unroll
    for (int k = 0; k < 16; ++k)
        a = fmaf(uu[wv][k], w[k * 64 + lane], a);
    float r1 = fmaxf(a, 0.f) * dv;
    h1bf[(size_t)v * 64 + lane] = (u16)bfr(r1);
}

// ---------------- layer-2 aggregation -> SoA hi/lo v planes ----------------
__global__ __launch_bounds__(256) void k_agg64p(const u16* __restrict__ h1bf,
                                                const float* __restrict__ dinv,
                                                const int* __restrict__ row_ptr, const int* __restrict__ col,
                                                u16* __restrict__ vhi, u16* __restrict__ vlo, int N) {
    int lane = threadIdx.x & 63;
    int v = blockIdx.x * 4 + (threadIdx.x >> 6);
    if (v >= N) return;
    int cp = lane & 15;  // uint2 index: channels 4cp..4cp+3
    int eg = lane >> 4;  // 4 edge groups
    int b = row_ptr[v];
    int e = row_ptr[v + 1];
    float s0 = 0.f, s1 = 0.f, s2 = 0.f, s3 = 0.f;
    const uint2* tbl = (const uint2*)h1bf;
#pragma unroll 2
    for (int i = b + eg; i < e; i += 4) {
        int c = col[i];
        uint2 pw = tbl[(size_t)c * 16 + cp];
        s0 += bf2f((u16)(pw.x & 0xffffu));
        s1 += bf2f((u16)(pw.x >> 16));
        s2 += bf2f((u16)(pw.y & 0xffffu));
        s3 += bf2f((u16)(pw.y >> 16));
    }
    s0 += __shfl_xor(s0, 16, 64); s1 += __shfl_xor(s1, 16, 64);
    s2 += __shfl_xor(s2, 16, 64); s3 += __shfl_xor(s3, 16, 64);
    s0 += __shfl_xor(s0, 32, 64); s1 += __shfl_xor(s1, 32, 64);
    s2 += __shfl_xor(s2, 32, 64); s3 += __shfl_xor(s3, 32, 64);
    if (eg == 0) {
        uint2 sw = tbl[(size_t)v * 16 + cp];
        float dv = dinv[v];
        float t0 = dv * (s0 + bf2f((u16)(sw.x & 0xffffu)));
        float t1 = dv * (s1 + bf2f((u16)(sw.x >> 16)));
        float t2 = dv * (s2 + bf2f((u16)(sw.y & 0xffffu)));
        float t3 = dv * (s3 + bf2f((u16)(sw.y >> 16)));
        u16 h0, l0, h1v, l1v, h2v, l2v, h3, l3;
        bsplit(t0, h0, l0); bsplit(t1, h1v, l1v);
        bsplit(t2, h2v, l2v); bsplit(t3, h3, l3);
        uint2 oh, ol;
        oh.x = (unsigned)h0 | ((unsigned)h1v << 16);
        oh.y = (unsigned)h2v | ((unsigned)h3 << 16);
        ol.x = (unsigned)l0 | ((unsigned)l1v << 16);
        ol.y = (unsigned)l2v | ((unsigned)l3 << 16);
        *(uint2*)(vhi + (size_t)v * 64 + 4 * cp) = oh;
        *(uint2*)(vlo + (size_t)v * 64 + 4 * cp) = ol;
    }
}

// ---------------- fused h2 MFMA + LSTM MFMA ----------------
// block = 256 (4 waves), 64-row tile. LDS: 64 rows x 392 B (hi + lo planes).
// K layout: kc0..3 = h2(64ch), kc4..11 = h_prev(128ch).
// SoA inputs -> staging is raw uint4 copies (no repack).
// LSTM subtiles s=0,1 processed sequentially: acc = 64 regs, 3 blocks/CU.
__global__ __launch_bounds__(256, 3) void k_h2lstm(const u16* __restrict__ vhi, const u16* __restrict__ vlo,
                                                   const u16* __restrict__ w2thi, const u16* __restrict__ w2tlo,
                                                   const float* __restrict__ b2,
                                                   u16* __restrict__ hhi, u16* __restrict__ hlo,
                                                   float* __restrict__ cbuf,
                                                   const u16* __restrict__ whi, const u16* __restrict__ wlo,
                                                   const float* __restrict__ b_ih, const float* __restrict__ b_hh,
                                                   int N) {
    __shared__ __align__(16) char lds_hi[64 * 392];
    __shared__ __align__(16) char lds_lo[64 * 392];
    int tid = threadIdx.x;
    int lane = tid & 63;
    int w = tid >> 6;
    int row0 = blockIdx.x * 64;
    int l31 = lane & 31;
    int hf = lane >> 5;

    // ---- phase 0a: stage v -> kc8..11 (raw copies) ----
    for (int idx = tid; idx < 512; idx += 256) {
        int m = idx >> 3, c8 = idx & 7;
        int row = row0 + m;
        uint4 vh = make_uint4(0, 0, 0, 0), vl = make_uint4(0, 0, 0, 0);
        if (row < N) {
            vh = *(const uint4*)(vhi + (size_t)row * 64 + c8 * 8);
            vl = *(const uint4*)(vlo + (size_t)row * 64 + c8 * 8);
        }
        size_t bo = (size_t)m * 392 + 256 + (size_t)c8 * 16;
        *(uint4*)(lds_hi + bo) = vh;
        *(uint4*)(lds_lo + bo) = vl;
    }
    // ---- phase 0b: stage h_prev cols 0..63 -> kc4..7 ----
    for (int idx = tid; idx < 512; idx += 256) {
        int m = idx >> 3, c8 = idx & 7;
        int row = row0 + m;
        uint4 vh = make_uint4(0, 0, 0, 0), vl = make_uint4(0, 0, 0, 0);
        if (row < N) {
            vh = *(const uint4*)(hhi + (size_t)row * 128 + c8 * 8);
            vl = *(const uint4*)(hlo + (size_t)row * 128 + c8 * 8);
        }
        size_t bo = (size_t)m * 392 + 128 + (size_t)c8 * 16;
        *(uint4*)(lds_hi + bo) = vh;
        *(uint4*)(lds_lo + bo) = vl;
    }
    __syncthreads();

    // ---- phase 1: h2 = relu(v @ W2 + b2), one 32x32 tile per wave ----
    {
        int rowsub = w & 1, colsub = w >> 1;
        int c = colsub * 32 + l31;
        f32x16 acc;
#pragma unroll
        for (int r = 0; r < 16; ++r) acc[r] = 0.f;
        const char* ah = lds_hi + (size_t)(rowsub * 32 + l31) * 392 + 256 + (size_t)hf * 16;
        const char* al = lds_lo + (size_t)(rowsub * 32 + l31) * 392 + 256 + (size_t)hf * 16;
        const char* bh = (const char*)w2thi + (size_t)c * 128 + (size_t)hf * 16;
        const char* bl = (const char*)w2tlo + (size_t)c * 128 + (size_t)hf * 16;
#pragma unroll
        for (int kc = 0; kc < 4; ++kc) {
            AF Ahi, Alo, Bhi, Blo;
            Ahi.q[0] = *(const u64*)(ah + kc * 32); Ahi.q[1] = *(const u64*)(ah + kc * 32 + 8);
            Alo.q[0] = *(const u64*)(al + kc * 32); Alo.q[1] = *(const u64*)(al + kc * 32 + 8);
            Bhi.v = *(const s16x8*)(bh + kc * 32);
            Blo.v = *(const s16x8*)(bl + kc * 32);
            acc = __builtin_amdgcn_mfma_f32_32x32x16_bf16(Ahi.v, Bhi.v, acc, 0, 0, 0);
            acc = __builtin_amdgcn_mfma_f32_32x32x16_bf16(Alo.v, Bhi.v, acc, 0, 0, 0);
            acc = __builtin_amdgcn_mfma_f32_32x32x16_bf16(Ahi.v, Blo.v, acc, 0, 0, 0);
        }
        float bv = b2[c];
#pragma unroll
        for (int r = 0; r < 16; ++r) {
            int rl = (r & 3) + 8 * (r >> 2) + 4 * hf;
            int m = rowsub * 32 + rl;
            float val = fmaxf(acc[r] + bv, 0.f);
            u16 hh, ll;
            bsplit(val, hh, ll);
            size_t bo = (size_t)m * 392 + (size_t)c * 2;
            *(u16*)(lds_hi + bo) = hh;
            *(u16*)(lds_lo + bo) = ll;
        }
    }
    __syncthreads();

    // ---- phase 2: stage h_prev cols 64..127 -> kc8..11 (v dead) ----
    for (int idx = tid; idx < 512; idx += 256) {
        int m = idx >> 3, c8 = idx & 7;
        int row = row0 + m;
        uint4 vh = make_uint4(0, 0, 0, 0), vl = make_uint4(0, 0, 0, 0);
        if (row < N) {
            vh = *(const uint4*)(hhi + (size_t)row * 128 + 64 + c8 * 8);
            vl = *(const uint4*)(hlo + (size_t)row * 128 + 64 + c8 * 8);
        }
        size_t bo = (size_t)m * 392 + 256 + (size_t)c8 * 16;
        *(uint4*)(lds_hi + bo) = vh;
        *(uint4*)(lds_lo + bo) = vl;
    }
    __syncthreads();

    // ---- phase 3: LSTM gates, subtiles sequential (acc = 64 regs) ----
    int col_j = w * 32 + l31;
    const char* whc = (const char*)whi;
    const char* wlc = (const char*)wlo;
    size_t bbase[4];
#pragma unroll
    for (int g = 0; g < 4; ++g) bbase[g] = (size_t)(g * 128 + col_j) * 384 + (size_t)hf * 16;
    float bi = b_ih[col_j] + b_hh[col_j];
    float bff = b_ih[128 + col_j] + b_hh[128 + col_j];
    float bg = b_ih[256 + col_j] + b_hh[256 + col_j];
    float bo = b_ih[384 + col_j] + b_hh[384 + col_j];

    for (int s = 0; s < 2; ++s) {
        f32x16 acc[4];
#pragma unroll
        for (int g = 0; g < 4; ++g)
#pragma unroll
            for (int r = 0; r < 16; ++r) acc[g][r] = 0.f;
        size_t abase = (size_t)(s * 32 + l31) * 392 + (size_t)hf * 16;
#pragma unroll
        for (int kc = 0; kc < 12; ++kc) {
            AF ahi, alo;
            size_t a0 = abase + (size_t)kc * 32;
            ahi.q[0] = *(const u64*)(lds_hi + a0); ahi.q[1] = *(const u64*)(lds_hi + a0 + 8);
            alo.q[0] = *(const u64*)(lds_lo + a0); alo.q[1] = *(const u64*)(lds_lo + a0 + 8);
            AF bhi[4], blo[4];
#pragma unroll
            for (int g = 0; g < 4; ++g) {
                size_t bo2 = bbase[g] + (size_t)kc * 32;
                bhi[g].v = *(const s16x8*)(whc + bo2);
                blo[g].v = *(const s16x8*)(wlc + bo2);
            }
#pragma unroll
            for (int g = 0; g < 4; ++g) {
                acc[g] = __builtin_amdgcn_mfma_f32_32x32x16_bf16(ahi.v, bhi[g].v, acc[g], 0, 0, 0);
                acc[g] = __builtin_amdgcn_mfma_f32_32x32x16_bf16(alo.v, bhi[g].v, acc[g], 0, 0, 0);
                acc[g] = __builtin_amdgcn_mfma_f32_32x32x16_bf16(ahi.v, blo[g].v, acc[g], 0, 0, 0);
            }
        }
#pragma unroll
        for (int r = 0; r < 16; ++r) {
            int rl = (r & 3) + 8 * (r >> 2) + 4 * hf;
            int row = row0 + s * 32 + rl;
            if (row < N) {
                size_t off = (size_t)row * 128 + col_j;
                float iv = sigf(acc[0][r] + bi);
                float fv = sigf(acc[1][r] + bff);
                float gv = tanhfast(acc[2][r] + bg);
                float ov = sigf(acc[3][r] + bo);
                float cnew = fmaf(fv, cbuf[off], iv * gv);
                float hnew = ov * tanhfast(cnew);
                cbuf[off] = cnew;
                u16 hh, hl;
                bsplit(hnew, hh, hl);
                hhi[off] = hh;
                hlo[off] = hl;
            }
        }
    }
}

// ---------------- MLP head (SoA h planes) ----------------
__global__ __launch_bounds__(256) void k_mlp(const u16* __restrict__ hhi, const u16* __restrict__ hlo,
                                             const float* __restrict__ Wf1, const float* __restrict__ bf1,
                                             const float* __restrict__ Wf2, const float* __restrict__ bf2,
                                             float* __restrict__ out, int N) {
    int lane = threadIdx.x & 63;
    int v = blockIdx.x * 4 + (threadIdx.x >> 6);
    if (v >= N) return;
    int j = lane & 31;
    int half = lane >> 5;
    const u16* hh = hhi + (size_t)v * 128 + half * 64;
    const u16* hl = hlo + (size_t)v * 128 + half * 64;
    float s = 0.f;
#pragma unroll
    for (int k = 0; k < 64; ++k) {
        float hv = bf2f(hh[k]) + bf2f(hl[k]);
        s = fmaf(hv, Wf1[(half * 64 + k) * 32 + j], s);
    }
    s += __shfl_down(s, 32, 64);
    float z = fmaxf(s + bf1[j], 0.f);
    float p = z * Wf2[j];
#pragma unroll
    for (int off = 16; off > 0; off >>= 1) p += __shfl_down(p, off, 64);
    if (lane == 0) out[v] = p + bf2[0];
}

extern "C" void kernel_launch(void* const* d_in, const int* in_sizes, int n_in,
                              void* d_out, int out_size, void* d_ws, size_t ws_size,
                              hipStream_t stream) {
    const float* x_seq = (const float*)d_in[0];
    const int* eidx = (const int*)d_in[1];
    const float* W1 = (const float*)d_in[2];
    const float* b1 = (const float*)d_in[3];
    const float* W2 = (const float*)d_in[4];
    const float* b2 = (const float*)d_in[5];
    const float* W_ih = (const float*)d_in[6];
    const float* W_hh = (const float*)d_in[7];
    const float* b_ih = (const float*)d_in[8];
    const float* b_hh = (const float*)d_in[9];
    const float* Wf1 = (const float*)d_in[10];
    const float* bf1 = (const float*)d_in[11];
    const float* Wf2 = (const float*)d_in[12];
    const float* bf2 = (const float*)d_in[13];

    int N = out_size;                 // 50000
    int E = in_sizes[1] / 2;          // 1,600,000
    int T = in_sizes[0] / (N * 16);   // 24
    const int* srcp = eidx;
    const int* dstp = eidx + E;

    char* ws = (char*)d_ws;
    size_t off = 0;
    auto alloc = [&](size_t bytes) -> char* {
        char* p = ws + off;
        off = (off + bytes + 255) & ~(size_t)255;
        return p;
    };
    int* deg = (int*)alloc((size_t)N * 4);
    int* row_ptr = (int*)alloc(((size_t)N + 1) * 4);
    int* cursor = (int*)alloc((size_t)N * 4);
    int* col = (int*)alloc((size_t)E * 4);
    int* partial = (int*)alloc(260 * 4);
    float* dinv = (float*)alloc((size_t)N * 4);
    u16* h1bf = (u16*)alloc((size_t)N * 64 * 2);
    u16* vhi = (u16*)alloc((size_t)N * 64 * 2);
    u16* vlo = (u16*)alloc((size_t)N * 64 * 2);
    u16* hhi = (u16*)alloc((size_t)N * 128 * 2);
    u16* hlo = (u16*)alloc((size_t)N * 128 * 2);
    float* cbuf = (float*)alloc((size_t)N * 128 * 4);
    u16* whi = (u16*)alloc((size_t)512 * 192 * 2);
    u16* wlo = (u16*)alloc((size_t)512 * 192 * 2);
    u16* w2thi = (u16*)alloc((size_t)64 * 64 * 2);
    u16* w2tlo = (u16*)alloc((size_t)64 * 64 * 2);

    hipMemsetAsync(deg, 0, (size_t)N * 4, stream);
    hipMemsetAsync(hhi, 0, (size_t)N * 128 * 2, stream);
    hipMemsetAsync(hlo, 0, (size_t)N * 128 * 2, stream);
    hipMemsetAsync(cbuf, 0, (size_t)N * 128 * 4, stream);

    int nb = (N + 255) / 256;  // 196 <= 256
    k_count<<<(E + 255) / 256, 256, 0, stream>>>(dstp, E, deg);
    k_dinv<<<(N + 255) / 256, 256, 0, stream>>>(deg, dinv, N);
    k_scan_part<<<nb, 256, 0, stream>>>(deg, partial, N);
    k_scan_top<<<1, 256, 0, stream>>>(partial, nb);
    k_scan_fill<<<nb, 256, 0, stream>>>(deg, partial, row_ptr, cursor, N);
    int halfN = N / 2;
    k_fill_range<<<(E + 255) / 256, 256, 0, stream>>>(srcp, dstp, E, cursor, col, 0, halfN);
    k_fill_range<<<(E + 255) / 256, 256, 0, stream>>>(srcp, dstp, E, cursor, col, halfN, N);
    k_wprep<<<(512 * 192 + 255) / 256, 256, 0, stream>>>(W_ih, W_hh, whi, wlo);
    k_w2prep<<<(64 * 64 + 255) / 256, 256, 0, stream>>>(W2, w2thi, w2tlo);

    int node_wave_blocks = (N + 3) / 4;
    int tile_blocks = (N + 63) / 64;
    for (int t = 0; t < T; ++t) {
        const float* xt = x_seq + (size_t)t * N * 16;
        k_gcn1<<<node_wave_blocks, 256, 0, stream>>>(xt, dinv, row_ptr, col, W1, b1, h1bf, N);
        k_agg64p<<<node_wave_blocks, 256, 0, stream>>>(h1bf, dinv, row_ptr, col, vhi, vlo, N);
        k_h2lstm<<<tile_blocks, 256, 0, stream>>>(vhi, vlo, w2thi, w2tlo, b2, hhi, hlo, cbuf,
                                                  whi, wlo, b_ih, b_hh, N);
    }
    k_mlp<<<node_wave_blocks, 256, 0, stream>>>(hhi, hlo, Wf1, bf1, Wf2, bf2, (float*)d_out, N);
}

// Round 8
// 3950.754 us; speedup vs baseline: 2.1356x; 2.1356x over previous
//
#include <hip/hip_runtime.h>
#include <hip/hip_bf16.h>
#include <math.h>

// SpatialTemporalModel: GCN(2-layer) x24 -> LSTM(128) -> MLP head.
// Round 8: fix round-7 scratch-spill regression (launch_bounds(256,3) forced
// accumulator spills -> 240MB symmetric R/W scratch traffic). Phase 3 back to
// round-6 interleaved acc[2][4] under (256,2); KEEP SoA hi/lo staging (no
// repack VALU); NEW: prefetch cbuf into regs during phase 0 so the gating
// epilogue never stalls on cold HBM reads.

typedef short s16x8 __attribute__((ext_vector_type(8)));
typedef float f32x16 __attribute__((ext_vector_type(16)));
typedef unsigned long long u64;
typedef unsigned short u16;
union AF { s16x8 v; u64 q[2]; uint4 u4; };

__device__ __forceinline__ float sigf(float x) { return 1.f / (1.f + __expf(-x)); }
__device__ __forceinline__ float tanhfast(float x) { return 1.f - 2.f / (1.f + __expf(2.f * x)); }

// round-to-nearest-even f32 -> bf16 bits
__device__ __forceinline__ unsigned bfr(float x) {
    union { float f; unsigned u; } c; c.f = x;
    return (c.u + 0x7fffu + ((c.u >> 16) & 1u)) >> 16;
}
__device__ __forceinline__ void bsplit(float x, u16& hi, u16& lo) {
    unsigned h = bfr(x);
    union { unsigned u; float f; } hf; hf.u = h << 16;
    hi = (u16)h;
    lo = (u16)bfr(x - hf.f);
}
__device__ __forceinline__ float bf2f(u16 b) {
    union { unsigned u; float f; } c; c.u = ((unsigned)b) << 16;
    return c.f;
}

// ---------------- CSR build ----------------
__global__ void k_count(const int* __restrict__ dst, int E, int* __restrict__ deg) {
    int e = blockIdx.x * blockDim.x + threadIdx.x;
    if (e < E) atomicAdd(&deg[dst[e]], 1);
}

__global__ void k_dinv(const int* __restrict__ deg, float* __restrict__ dinv, int N) {
    int v = blockIdx.x * blockDim.x + threadIdx.x;
    if (v < N) dinv[v] = rsqrtf((float)deg[v] + 1.0f);
}

__global__ __launch_bounds__(256) void k_scan_part(const int* __restrict__ deg, int* __restrict__ partial, int N) {
    int tid = threadIdx.x;
    int i = blockIdx.x * 256 + tid;
    int v = (i < N) ? deg[i] : 0;
    int s = v;
#pragma unroll
    for (int off = 1; off < 64; off <<= 1) s += __shfl_xor(s, off, 64);
    __shared__ int ws[4];
    if ((tid & 63) == 0) ws[tid >> 6] = s;
    __syncthreads();
    if (tid == 0) partial[blockIdx.x] = ws[0] + ws[1] + ws[2] + ws[3];
}

__global__ __launch_bounds__(256) void k_scan_top(int* __restrict__ partial, int nb) {
    __shared__ int sm[256];
    int t = threadIdx.x;
    int x = (t < nb) ? partial[t] : 0;
    sm[t] = x;
    __syncthreads();
#pragma unroll
    for (int off = 1; off < 256; off <<= 1) {
        int y = (t >= off) ? sm[t - off] : 0;
        __syncthreads();
        sm[t] += y;
        __syncthreads();
    }
    if (t < nb) partial[t] = sm[t] - x;  // exclusive
}

__global__ __launch_bounds__(256) void k_scan_fill(const int* __restrict__ deg, const int* __restrict__ partial,
                                                   int* __restrict__ row_ptr, int* __restrict__ cursor, int N) {
    int tid = threadIdx.x;
    int lane = tid & 63;
    int wv = tid >> 6;
    int i = blockIdx.x * 256 + tid;
    int v = (i < N) ? deg[i] : 0;
    int incl = v;
#pragma unroll
    for (int off = 1; off < 64; off <<= 1) {
        int y = __shfl_up(incl, off, 64);
        if (lane >= off) incl += y;
    }
    __shared__ int ws[4];
    if (lane == 63) ws[wv] = incl;
    __syncthreads();
    int woff = 0;
    for (int w = 0; w < wv; ++w) woff += ws[w];
    int excl = incl - v + woff + partial[blockIdx.x];
    if (i < N) {
        row_ptr[i] = excl;
        cursor[i] = excl;
        if (i == N - 1) row_ptr[N] = excl + v;
    }
}

__global__ void k_fill_range(const int* __restrict__ src, const int* __restrict__ dst, int E,
                             int* __restrict__ cursor, int* __restrict__ col, int lo, int hi) {
    int e = blockIdx.x * blockDim.x + threadIdx.x;
    if (e < E) {
        int d = dst[e];
        if (d >= lo && d < hi) {
            int p = atomicAdd(&cursor[d], 1);
            col[p] = src[e];
        }
    }
}

// ---------------- weight prep ----------------
__global__ void k_wprep(const float* __restrict__ W_ih, const float* __restrict__ W_hh,
                        u16* __restrict__ whi, u16* __restrict__ wlo) {
    int i = blockIdx.x * 256 + threadIdx.x;
    if (i >= 512 * 192) return;
    int g = i / 192, k = i - g * 192;
    float wv = (k < 64) ? W_ih[g * 64 + k] : W_hh[g * 128 + (k - 64)];
    u16 h, l;
    bsplit(wv, h, l);
    whi[i] = h;
    wlo[i] = l;
}

__global__ void k_w2prep(const float* __restrict__ W2,
                         u16* __restrict__ w2thi, u16* __restrict__ w2tlo) {
    int i = blockIdx.x * 256 + threadIdx.x;
    if (i >= 64 * 64) return;
    int c = i >> 6, k = i & 63;
    u16 h, l;
    bsplit(W2[k * 64 + c], h, l);
    w2thi[c * 64 + k] = h;
    w2tlo[c * 64 + k] = l;
}

// ---------------- fused layer-1: agg16 + h1 GEMM in-wave ----------------
__global__ __launch_bounds__(256) void k_gcn1(const float* __restrict__ x, const float* __restrict__ dinv,
                                              const int* __restrict__ row_ptr, const int* __restrict__ col,
                                              const float* __restrict__ W1, const float* __restrict__ b1,
                                              u16* __restrict__ h1bf, int N) {
    __shared__ float w[16 * 64];
    __shared__ float uu[4][16];
    int tid = threadIdx.x;
    ((float4*)w)[tid] = ((const float4*)W1)[tid];
    __syncthreads();
    int lane = tid & 63;
    int wv = tid >> 6;
    int v = blockIdx.x * 4 + wv;
    if (v >= N) return;
    int cg = lane & 7;   // channel pair 2cg, 2cg+1
    int eg = lane >> 3;  // 8 edge groups
    int b = row_ptr[v];
    int e = row_ptr[v + 1];
    float s0 = 0.f, s1 = 0.f;
#pragma unroll 2
    for (int i = b + eg; i < e; i += 8) {
        int c = col[i];
        float2 xv = *(const float2*)(x + (size_t)c * 16 + 2 * cg);
        float dc = dinv[c];
        s0 = fmaf(dc, xv.x, s0);
        s1 = fmaf(dc, xv.y, s1);
    }
    s0 += __shfl_xor(s0, 8, 64);  s1 += __shfl_xor(s1, 8, 64);
    s0 += __shfl_xor(s0, 16, 64); s1 += __shfl_xor(s1, 16, 64);
    s0 += __shfl_xor(s0, 32, 64); s1 += __shfl_xor(s1, 32, 64);
    float dv = dinv[v];
    if (eg == 0) {
        float2 xv = *(const float2*)(x + (size_t)v * 16 + 2 * cg);
        uu[wv][2 * cg]     = dv * fmaf(dv, xv.x, s0);
        uu[wv][2 * cg + 1] = dv * fmaf(dv, xv.y, s1);
    }
    float a = b1[lane];
#pragma unroll
    for (int k = 0; k < 16; ++k)
        a = fmaf(uu[wv][k], w[k * 64 + lane], a);
    float r1 = fmaxf(a, 0.f) * dv;
    h1bf[(size_t)v * 64 + lane] = (u16)bfr(r1);
}

// ---------------- layer-2 aggregation -> SoA hi/lo v planes ----------------
__global__ __launch_bounds__(256) void k_agg64p(const u16* __restrict__ h1bf,
                                                const float* __restrict__ dinv,
                                                const int* __restrict__ row_ptr, const int* __restrict__ col,
                                                u16* __restrict__ vhi, u16* __restrict__ vlo, int N) {
    int lane = threadIdx.x & 63;
    int v = blockIdx.x * 4 + (threadIdx.x >> 6);
    if (v >= N) return;
    int cp = lane & 15;  // uint2 index: channels 4cp..4cp+3
    int eg = lane >> 4;  // 4 edge groups
    int b = row_ptr[v];
    int e = row_ptr[v + 1];
    float s0 = 0.f, s1 = 0.f, s2 = 0.f, s3 = 0.f;
    const uint2* tbl = (const uint2*)h1bf;
#pragma unroll 2
    for (int i = b + eg; i < e; i += 4) {
        int c = col[i];
        uint2 pw = tbl[(size_t)c * 16 + cp];
        s0 += bf2f((u16)(pw.x & 0xffffu));
        s1 += bf2f((u16)(pw.x >> 16));
        s2 += bf2f((u16)(pw.y & 0xffffu));
        s3 += bf2f((u16)(pw.y >> 16));
    }
    s0 += __shfl_xor(s0, 16, 64); s1 += __shfl_xor(s1, 16, 64);
    s2 += __shfl_xor(s2, 16, 64); s3 += __shfl_xor(s3, 16, 64);
    s0 += __shfl_xor(s0, 32, 64); s1 += __shfl_xor(s1, 32, 64);
    s2 += __shfl_xor(s2, 32, 64); s3 += __shfl_xor(s3, 32, 64);
    if (eg == 0) {
        uint2 sw = tbl[(size_t)v * 16 + cp];
        float dv = dinv[v];
        float t0 = dv * (s0 + bf2f((u16)(sw.x & 0xffffu)));
        float t1 = dv * (s1 + bf2f((u16)(sw.x >> 16)));
        float t2 = dv * (s2 + bf2f((u16)(sw.y & 0xffffu)));
        float t3 = dv * (s3 + bf2f((u16)(sw.y >> 16)));
        u16 h0, l0, h1v, l1v, h2v, l2v, h3, l3;
        bsplit(t0, h0, l0); bsplit(t1, h1v, l1v);
        bsplit(t2, h2v, l2v); bsplit(t3, h3, l3);
        uint2 oh, ol;
        oh.x = (unsigned)h0 | ((unsigned)h1v << 16);
        oh.y = (unsigned)h2v | ((unsigned)h3 << 16);
        ol.x = (unsigned)l0 | ((unsigned)l1v << 16);
        ol.y = (unsigned)l2v | ((unsigned)l3 << 16);
        *(uint2*)(vhi + (size_t)v * 64 + 4 * cp) = oh;
        *(uint2*)(vlo + (size_t)v * 64 + 4 * cp) = ol;
    }
}

// ---------------- fused h2 MFMA + LSTM MFMA ----------------
// block = 256 (4 waves), 64-row tile. LDS: 64 rows x 392 B (hi + lo planes).
// K layout: kc0..3 = h2(64ch), kc4..11 = h_prev(128ch).
// Phase 0 also PREFETCHES cbuf for this thread's epilogue rows (hides HBM
// latency behind staging + MFMA). Phase 3 = round-6 interleaved acc[2][4],
// launch_bounds(256,2) -- NO min-waves-3 (that spilled acc to scratch, r7).
__global__ __launch_bounds__(256, 2) void k_h2lstm(const u16* __restrict__ vhi, const u16* __restrict__ vlo,
                                                   const u16* __restrict__ w2thi, const u16* __restrict__ w2tlo,
                                                   const float* __restrict__ b2,
                                                   u16* __restrict__ hhi, u16* __restrict__ hlo,
                                                   float* __restrict__ cbuf,
                                                   const u16* __restrict__ whi, const u16* __restrict__ wlo,
                                                   const float* __restrict__ b_ih, const float* __restrict__ b_hh,
                                                   int N) {
    __shared__ __align__(16) char lds_hi[64 * 392];
    __shared__ __align__(16) char lds_lo[64 * 392];
    int tid = threadIdx.x;
    int lane = tid & 63;
    int w = tid >> 6;
    int row0 = blockIdx.x * 64;
    int l31 = lane & 31;
    int hf = lane >> 5;
    int col_j = w * 32 + l31;

    // ---- cbuf prefetch for the gating epilogue (issued first, used last) ----
    float cc[2][16];
#pragma unroll
    for (int s = 0; s < 2; ++s)
#pragma unroll
        for (int r = 0; r < 16; ++r) {
            int rl = (r & 3) + 8 * (r >> 2) + 4 * hf;
            int row = row0 + s * 32 + rl;
            cc[s][r] = (row < N) ? cbuf[(size_t)row * 128 + col_j] : 0.f;
        }

    // ---- phase 0a: stage v -> kc8..11 (raw copies) ----
    for (int idx = tid; idx < 512; idx += 256) {
        int m = idx >> 3, c8 = idx & 7;
        int row = row0 + m;
        uint4 vh = make_uint4(0, 0, 0, 0), vl = make_uint4(0, 0, 0, 0);
        if (row < N) {
            vh = *(const uint4*)(vhi + (size_t)row * 64 + c8 * 8);
            vl = *(const uint4*)(vlo + (size_t)row * 64 + c8 * 8);
        }
        size_t bo = (size_t)m * 392 + 256 + (size_t)c8 * 16;
        *(uint4*)(lds_hi + bo) = vh;
        *(uint4*)(lds_lo + bo) = vl;
    }
    // ---- phase 0b: stage h_prev cols 0..63 -> kc4..7 ----
    for (int idx = tid; idx < 512; idx += 256) {
        int m = idx >> 3, c8 = idx & 7;
        int row = row0 + m;
        uint4 vh = make_uint4(0, 0, 0, 0), vl = make_uint4(0, 0, 0, 0);
        if (row < N) {
            vh = *(const uint4*)(hhi + (size_t)row * 128 + c8 * 8);
            vl = *(const uint4*)(hlo + (size_t)row * 128 + c8 * 8);
        }
        size_t bo = (size_t)m * 392 + 128 + (size_t)c8 * 16;
        *(uint4*)(lds_hi + bo) = vh;
        *(uint4*)(lds_lo + bo) = vl;
    }
    __syncthreads();

    // ---- phase 1: h2 = relu(v @ W2 + b2), one 32x32 tile per wave ----
    {
        int rowsub = w & 1, colsub = w >> 1;
        int c = colsub * 32 + l31;
        f32x16 acc;
#pragma unroll
        for (int r = 0; r < 16; ++r) acc[r] = 0.f;
        const char* ah = lds_hi + (size_t)(rowsub * 32 + l31) * 392 + 256 + (size_t)hf * 16;
        const char* al = lds_lo + (size_t)(rowsub * 32 + l31) * 392 + 256 + (size_t)hf * 16;
        const char* bh = (const char*)w2thi + (size_t)c * 128 + (size_t)hf * 16;
        const char* bl = (const char*)w2tlo + (size_t)c * 128 + (size_t)hf * 16;
#pragma unroll
        for (int kc = 0; kc < 4; ++kc) {
            AF Ahi, Alo, Bhi, Blo;
            Ahi.q[0] = *(const u64*)(ah + kc * 32); Ahi.q[1] = *(const u64*)(ah + kc * 32 + 8);
            Alo.q[0] = *(const u64*)(al + kc * 32); Alo.q[1] = *(const u64*)(al + kc * 32 + 8);
            Bhi.v = *(const s16x8*)(bh + kc * 32);
            Blo.v = *(const s16x8*)(bl + kc * 32);
            acc = __builtin_amdgcn_mfma_f32_32x32x16_bf16(Ahi.v, Bhi.v, acc, 0, 0, 0);
            acc = __builtin_amdgcn_mfma_f32_32x32x16_bf16(Alo.v, Bhi.v, acc, 0, 0, 0);
            acc = __builtin_amdgcn_mfma_f32_32x32x16_bf16(Ahi.v, Blo.v, acc, 0, 0, 0);
        }
        float bv = b2[c];
#pragma unroll
        for (int r = 0; r < 16; ++r) {
            int rl = (r & 3) + 8 * (r >> 2) + 4 * hf;
            int m = rowsub * 32 + rl;
            float val = fmaxf(acc[r] + bv, 0.f);
            u16 hh, ll;
            bsplit(val, hh, ll);
            size_t bo = (size_t)m * 392 + (size_t)c * 2;
            *(u16*)(lds_hi + bo) = hh;
            *(u16*)(lds_lo + bo) = ll;
        }
    }
    __syncthreads();

    // ---- phase 2: stage h_prev cols 64..127 -> kc8..11 (v dead) ----
    for (int idx = tid; idx < 512; idx += 256) {
        int m = idx >> 3, c8 = idx & 7;
        int row = row0 + m;
        uint4 vh = make_uint4(0, 0, 0, 0), vl = make_uint4(0, 0, 0, 0);
        if (row < N) {
            vh = *(const uint4*)(hhi + (size_t)row * 128 + 64 + c8 * 8);
            vl = *(const uint4*)(hlo + (size_t)row * 128 + 64 + c8 * 8);
        }
        size_t bo = (size_t)m * 392 + 256 + (size_t)c8 * 16;
        *(uint4*)(lds_hi + bo) = vh;
        *(uint4*)(lds_lo + bo) = vl;
    }
    __syncthreads();

    // ---- phase 3: LSTM gates, interleaved subtiles (round-6 proven) ----
    f32x16 acc[2][4];
#pragma unroll
    for (int s = 0; s < 2; ++s)
#pragma unroll
        for (int g = 0; g < 4; ++g)
#pragma unroll
            for (int r = 0; r < 16; ++r) acc[s][g][r] = 0.f;

    const char* whc = (const char*)whi;
    const char* wlc = (const char*)wlo;
    size_t bbase[4];
#pragma unroll
    for (int g = 0; g < 4; ++g) bbase[g] = (size_t)(g * 128 + col_j) * 384 + (size_t)hf * 16;
    size_t abase0 = (size_t)l31 * 392 + (size_t)hf * 16;
    size_t abase1 = (size_t)(32 + l31) * 392 + (size_t)hf * 16;

#pragma unroll
    for (int kc = 0; kc < 12; ++kc) {
        AF ahi0, alo0, ahi1, alo1;
        size_t a0 = abase0 + (size_t)kc * 32;
        size_t a1 = abase1 + (size_t)kc * 32;
        ahi0.q[0] = *(const u64*)(lds_hi + a0); ahi0.q[1] = *(const u64*)(lds_hi + a0 + 8);
        alo0.q[0] = *(const u64*)(lds_lo + a0); alo0.q[1] = *(const u64*)(lds_lo + a0 + 8);
        ahi1.q[0] = *(const u64*)(lds_hi + a1); ahi1.q[1] = *(const u64*)(lds_hi + a1 + 8);
        alo1.q[0] = *(const u64*)(lds_lo + a1); alo1.q[1] = *(const u64*)(lds_lo + a1 + 8);
        AF bhi[4], blo[4];
#pragma unroll
        for (int g = 0; g < 4; ++g) {
            size_t bo2 = bbase[g] + (size_t)kc * 32;
            bhi[g].v = *(const s16x8*)(whc + bo2);
            blo[g].v = *(const s16x8*)(wlc + bo2);
        }
#pragma unroll
        for (int g = 0; g < 4; ++g) {
            acc[0][g] = __builtin_amdgcn_mfma_f32_32x32x16_bf16(ahi0.v, bhi[g].v, acc[0][g], 0, 0, 0);
            acc[0][g] = __builtin_amdgcn_mfma_f32_32x32x16_bf16(alo0.v, bhi[g].v, acc[0][g], 0, 0, 0);
            acc[0][g] = __builtin_amdgcn_mfma_f32_32x32x16_bf16(ahi0.v, blo[g].v, acc[0][g], 0, 0, 0);
            acc[1][g] = __builtin_amdgcn_mfma_f32_32x32x16_bf16(ahi1.v, bhi[g].v, acc[1][g], 0, 0, 0);
            acc[1][g] = __builtin_amdgcn_mfma_f32_32x32x16_bf16(alo1.v, bhi[g].v, acc[1][g], 0, 0, 0);
            acc[1][g] = __builtin_amdgcn_mfma_f32_32x32x16_bf16(ahi1.v, blo[g].v, acc[1][g], 0, 0, 0);
        }
    }

    float bi = b_ih[col_j] + b_hh[col_j];
    float bff = b_ih[128 + col_j] + b_hh[128 + col_j];
    float bg = b_ih[256 + col_j] + b_hh[256 + col_j];
    float bo = b_ih[384 + col_j] + b_hh[384 + col_j];
#pragma unroll
    for (int s = 0; s < 2; ++s) {
#pragma unroll
        for (int r = 0; r < 16; ++r) {
            int rl = (r & 3) + 8 * (r >> 2) + 4 * hf;
            int row = row0 + s * 32 + rl;
            if (row < N) {
                size_t off = (size_t)row * 128 + col_j;
                float iv = sigf(acc[s][0][r] + bi);
                float fv = sigf(acc[s][1][r] + bff);
                float gv = tanhfast(acc[s][2][r] + bg);
                float ov = sigf(acc[s][3][r] + bo);
                float cnew = fmaf(fv, cc[s][r], iv * gv);
                float hnew = ov * tanhfast(cnew);
                cbuf[off] = cnew;
                u16 hh, hl;
                bsplit(hnew, hh, hl);
                hhi[off] = hh;
                hlo[off] = hl;
            }
        }
    }
}

// ---------------- MLP head (SoA h planes) ----------------
__global__ __launch_bounds__(256) void k_mlp(const u16* __restrict__ hhi, const u16* __restrict__ hlo,
                                             const float* __restrict__ Wf1, const float* __restrict__ bf1,
                                             const float* __restrict__ Wf2, const float* __restrict__ bf2,
                                             float* __restrict__ out, int N) {
    int lane = threadIdx.x & 63;
    int v = blockIdx.x * 4 + (threadIdx.x >> 6);
    if (v >= N) return;
    int j = lane & 31;
    int half = lane >> 5;
    const u16* hh = hhi + (size_t)v * 128 + half * 64;
    const u16* hl = hlo + (size_t)v * 128 + half * 64;
    float s = 0.f;
#pragma unroll
    for (int k = 0; k < 64; ++k) {
        float hv = bf2f(hh[k]) + bf2f(hl[k]);
        s = fmaf(hv, Wf1[(half * 64 + k) * 32 + j], s);
    }
    s += __shfl_down(s, 32, 64);
    float z = fmaxf(s + bf1[j], 0.f);
    float p = z * Wf2[j];
#pragma unroll
    for (int off = 16; off > 0; off >>= 1) p += __shfl_down(p, off, 64);
    if (lane == 0) out[v] = p + bf2[0];
}

extern "C" void kernel_launch(void* const* d_in, const int* in_sizes, int n_in,
                              void* d_out, int out_size, void* d_ws, size_t ws_size,
                              hipStream_t stream) {
    const float* x_seq = (const float*)d_in[0];
    const int* eidx = (const int*)d_in[1];
    const float* W1 = (const float*)d_in[2];
    const float* b1 = (const float*)d_in[3];
    const float* W2 = (const float*)d_in[4];
    const float* b2 = (const float*)d_in[5];
    const float* W_ih = (const float*)d_in[6];
    const float* W_hh = (const float*)d_in[7];
    const float* b_ih = (const float*)d_in[8];
    const float* b_hh = (const float*)d_in[9];
    const float* Wf1 = (const float*)d_in[10];
    const float* bf1 = (const float*)d_in[11];
    const float* Wf2 = (const float*)d_in[12];
    const float* bf2 = (const float*)d_in[13];

    int N = out_size;                 // 50000
    int E = in_sizes[1] / 2;          // 1,600,000
    int T = in_sizes[0] / (N * 16);   // 24
    const int* srcp = eidx;
    const int* dstp = eidx + E;

    char* ws = (char*)d_ws;
    size_t off = 0;
    auto alloc = [&](size_t bytes) -> char* {
        char* p = ws + off;
        off = (off + bytes + 255) & ~(size_t)255;
        return p;
    };
    int* deg = (int*)alloc((size_t)N * 4);
    int* row_ptr = (int*)alloc(((size_t)N + 1) * 4);
    int* cursor = (int*)alloc((size_t)N * 4);
    int* col = (int*)alloc((size_t)E * 4);
    int* partial = (int*)alloc(260 * 4);
    float* dinv = (float*)alloc((size_t)N * 4);
    u16* h1bf = (u16*)alloc((size_t)N * 64 * 2);
    u16* vhi = (u16*)alloc((size_t)N * 64 * 2);
    u16* vlo = (u16*)alloc((size_t)N * 64 * 2);
    u16* hhi = (u16*)alloc((size_t)N * 128 * 2);
    u16* hlo = (u16*)alloc((size_t)N * 128 * 2);
    float* cbuf = (float*)alloc((size_t)N * 128 * 4);
    u16* whi = (u16*)alloc((size_t)512 * 192 * 2);
    u16* wlo = (u16*)alloc((size_t)512 * 192 * 2);
    u16* w2thi = (u16*)alloc((size_t)64 * 64 * 2);
    u16* w2tlo = (u16*)alloc((size_t)64 * 64 * 2);

    hipMemsetAsync(deg, 0, (size_t)N * 4, stream);
    hipMemsetAsync(hhi, 0, (size_t)N * 128 * 2, stream);
    hipMemsetAsync(hlo, 0, (size_t)N * 128 * 2, stream);
    hipMemsetAsync(cbuf, 0, (size_t)N * 128 * 4, stream);

    int nb = (N + 255) / 256;  // 196 <= 256
    k_count<<<(E + 255) / 256, 256, 0, stream>>>(dstp, E, deg);
    k_dinv<<<(N + 255) / 256, 256, 0, stream>>>(deg, dinv, N);
    k_scan_part<<<nb, 256, 0, stream>>>(deg, partial, N);
    k_scan_top<<<1, 256, 0, stream>>>(partial, nb);
    k_scan_fill<<<nb, 256, 0, stream>>>(deg, partial, row_ptr, cursor, N);
    int halfN = N / 2;
    k_fill_range<<<(E + 255) / 256, 256, 0, stream>>>(srcp, dstp, E, cursor, col, 0, halfN);
    k_fill_range<<<(E + 255) / 256, 256, 0, stream>>>(srcp, dstp, E, cursor, col, halfN, N);
    k_wprep<<<(512 * 192 + 255) / 256, 256, 0, stream>>>(W_ih, W_hh, whi, wlo);
    k_w2prep<<<(64 * 64 + 255) / 256, 256, 0, stream>>>(W2, w2thi, w2tlo);

    int node_wave_blocks = (N + 3) / 4;
    int tile_blocks = (N + 63) / 64;
    for (int t = 0; t < T; ++t) {
        const float* xt = x_seq + (size_t)t * N * 16;
        k_gcn1<<<node_wave_blocks, 256, 0, stream>>>(xt, dinv, row_ptr, col, W1, b1, h1bf, N);
        k_agg64p<<<node_wave_blocks, 256, 0, stream>>>(h1bf, dinv, row_ptr, col, vhi, vlo, N);
        k_h2lstm<<<tile_blocks, 256, 0, stream>>>(vhi, vlo, w2thi, w2tlo, b2, hhi, hlo, cbuf,
                                                  whi, wlo, b_ih, b_hh, N);
    }
    k_mlp<<<node_wave_blocks, 256, 0, stream>>>(hhi, hlo, Wf1, bf1, Wf2, bf2, (float*)d_out, N);
}